// Round 1
// baseline (187.783 us; speedup 1.0000x reference)
//
#include <hip/hip_runtime.h>
#include <cstdint>

typedef __attribute__((ext_vector_type(8))) short short8;     // 8 bf16 (4 VGPRs)
typedef __attribute__((ext_vector_type(4))) float floatx4;
typedef __attribute__((ext_vector_type(2))) unsigned int uintx2;
typedef __attribute__((ext_vector_type(4))) unsigned int uintx4;

#define CS 18                    // LDS cell stride in words (16 kpair + 2 pad): conflict-free frag reads
#define A_WORDS (8 * 16 * CS)    // 8 h-rows x 16 w cells                  = 2304 words
#define B_ROWS  13               // 12 halo rows + 1 dump row for idle staging threads
#define B_WORDS (B_ROWS * 24 * CS)  // 13 rows x 24 col cells              = 5616 words
// LDS total = 2*(A_WORDS+B_WORDS)*4 = 63360 B  -> 2 blocks/CU (124 KB of 160)

__device__ __forceinline__ uint32_t pack2(float a, float b) {
    uint32_t ua = __builtin_bit_cast(uint32_t, a);
    uint32_t ub = __builtin_bit_cast(uint32_t, b);
    ua = (ua + 0x7FFFu + ((ua >> 16) & 1u)) >> 16;   // RNE (verified prev session, absmax 0.5)
    ub = (ub + 0x7FFFu + ((ub >> 16) & 1u)) >> 16;
    return ua | (ub << 16);                           // lo = even channel, hi = odd channel
}

__device__ __forceinline__ short8 frag_ld(const uint32_t* p) {
    uintx2 lo = *(const uintx2*)p;        // ds_read_b64 (cells 8B-aligned: CS*4=72 ≡ 0 mod 8)
    uintx2 hi = *(const uintx2*)(p + 2);
    uintx4 v = {lo.x, lo.y, hi.x, hi.y};
    return __builtin_bit_cast(short8, v);
}

// out[b, di*9+dj, h, w] = sum_c f1[b,c,h,w] * f2[b,c,h+di-4,w+dj-4]  (zero-padded)
// Occupancy redesign vs prev version: tile 8h x 16w, di split 5/4 across block pairs
//  -> acc 144->40 regs, LDS 144->62 KB, grid 256->1024, 2 blocks/CU, 4 waves/SIMD,
//     two independent barrier domains per CU (convoy smoothing).
__global__ __launch_bounds__(512, 4)
void corr_kernel(const float* __restrict__ f1, const float* __restrict__ f2,
                 float* __restrict__ out) {
    __shared__ uint32_t ldsA[2 * A_WORDS];
    __shared__ uint32_t ldsB[2 * B_WORDS];

    const int tid  = threadIdx.x;
    const int lane = tid & 63;
    const int wh   = tid >> 6;        // wave id == h sub-row (0..7)
    const int n15  = lane & 15;
    const int q    = lane >> 4;

    const int bid    = blockIdx.x;
    const int b      = bid & 7;         // batch in low bits: XCD (bid%8) partitioned by batch
    const int dihalf = (bid >> 3) & 1;  // di group: 0 -> di 0..4, 1 -> di 5..8 (bit 3: both types per XCD)
    const int ht     = (bid >> 4) & 7;  // h tile -> h0 = 8*ht
    const int wt     = bid >> 7;        // w tile (0..7) -> w0 = 16*wt

    const int w0 = wt * 16;
    const int h0 = ht * 8;
    const int h  = h0 + wh;

    const int diN    = dihalf ? 4 : 5;         // block-uniform
    const int diBase = dihalf * 5;
    const int ghBase = dihalf ? (h0 + 1) : (h0 - 4);  // f2 row of LDS B row 0

    const float* f1b = f1 + (size_t)b * 256 * 8192;
    const float* f2b = f2 + (size_t)b * 256 * 8192;

    // ---- A staging: 512 tasks, exactly 1/thread (always in-bounds)
    const int aw4 = tid & 3, akp = (tid >> 2) & 15, arow = tid >> 6;
    int aOffG = (2 * akp) * 8192 + (h0 + arow) * 128 + (w0 + 4 * aw4);  // element offset, chunk 0
    const int aLds = (arow * 16 + 4 * aw4) * CS + akp;

    // ---- B staging: 12 rows x 6 w4-groups x 16 kp = 1152 tasks; 3 rounds of 512
    //      (round 2: threads >= 128 are idle -> write zeros into dump row 12)
    int bOffG[3];
    int bLds[3];
    uint32_t bMask[3];
#pragma unroll
    for (int s = 0; s < 3; ++s) {
        int t = tid + 512 * s;
        int w4 = t % 6;
        int r2 = t / 6;
        int kp = r2 & 15, row = r2 >> 4;
        int gh = ghBase + row;
        int gw = w0 - 4 + 4 * w4;                 // vec4 fully in or fully out (w0 % 16 == 0)
        bool live = (t < 1152);
        bool inb  = live && ((unsigned)gh < 64u) && ((unsigned)gw < 128u);
        bOffG[s] = inb ? ((2 * kp) * 8192 + gh * 128 + gw) : 0;
        bLds[s]  = live ? ((row * 24 + 4 * w4) * CS + kp)
                        : ((12 * 24 + (tid & 7)) * CS);   // dump row, harmless zeros
        bMask[s] = inb ? 0xFFFFFFFFu : 0u;
    }

    floatx4 acc[5][2];
#pragma unroll
    for (int dl = 0; dl < 5; ++dl)
#pragma unroll
        for (int t = 0; t < 2; ++t)
            acc[dl][t] = (floatx4){0.f, 0.f, 0.f, 0.f};

    floatx4 rA[2], rB[3][2];
    uint32_t pkA[4], pkB[12];

    auto issue = [&]() {   // non-blocking global loads for the next chunk (32 ch = 16 kpairs)
        rA[0] = *(const floatx4*)(f1b + aOffG);
        rA[1] = *(const floatx4*)(f1b + aOffG + 8192);
        aOffG += 32 * 8192;
#pragma unroll
        for (int s = 0; s < 3; ++s) {
            rB[s][0] = *(const floatx4*)(f2b + bOffG[s]);
            rB[s][1] = *(const floatx4*)(f2b + bOffG[s] + 8192);
            bOffG[s] += 32 * 8192;
        }
    };
    auto packall = [&]() {
#pragma unroll
        for (int i = 0; i < 4; ++i)
            pkA[i] = pack2(rA[0][i], rA[1][i]);
#pragma unroll
        for (int s = 0; s < 3; ++s)
#pragma unroll
            for (int i = 0; i < 4; ++i)
                pkB[4 * s + i] = pack2(rB[s][0][i], rB[s][1][i]) & bMask[s];
    };

    issue();      // chunk 0
    packall();

    for (int ch = 0; ch < 8; ++ch) {
        uint32_t* bufA = ldsA + (ch & 1) * A_WORDS;
        uint32_t* bufB = ldsB + (ch & 1) * B_WORDS;

        // write current chunk's packed words
#pragma unroll
        for (int i = 0; i < 4; ++i)
            bufA[aLds + i * CS] = pkA[i];
#pragma unroll
        for (int s = 0; s < 3; ++s)
#pragma unroll
            for (int i = 0; i < 4; ++i)
                bufB[bLds[s] + i * CS] = pkB[4 * s + i];

        if (ch < 7) issue();          // next chunk's loads in flight across barrier + compute
        __syncthreads();              // buf[ch&1] complete for all threads

        const uint32_t* pa = bufA + (wh * 16 + n15) * CS + 4 * q;
        short8 a0 = frag_ld(pa);                       // m = w 0..15
        const uint32_t* pb = bufB + (wh * 24 + n15) * CS + 4 * q;
#pragma unroll
        for (int dl = 0; dl < 5; ++dl) {
            if (dl < diN) {                            // uniform branch (set1 skips dl=4)
                const uint32_t* p = pb + dl * (24 * CS);
                short8 b0 = frag_ld(p);                // B cols cb = 0..15  (f2 w = w0-4+cb)
                short8 b1 = frag_ld(p + 8 * CS);       // B cols cb = 8..23 (overlap; dedupe in epilogue)
                acc[dl][0] = __builtin_amdgcn_mfma_f32_16x16x32_bf16(a0, b0, acc[dl][0], 0, 0, 0);
                acc[dl][1] = __builtin_amdgcn_mfma_f32_16x16x32_bf16(a0, b1, acc[dl][1], 0, 0, 0);
            }
        }
        if (ch < 7) packall();        // consume in-flight loads after compute
        // single barrier/chunk: buffer reuse at ch+2 is ordered by the ch+1 barrier
    }

    // ---- epilogue: band extraction. D[m'=4q+r][n'=n15]; tile t at col offset 8t:
    // cb = 8t + n', dj = cb - m', keep 0..8; t1 only stores cb >= 16 (dedupe of overlap cols 8..15)
    const size_t base = ((size_t)b * 81) * 8192 + (size_t)h * 128 + w0;
#pragma unroll
    for (int dl = 0; dl < 5; ++dl) {
        if (dl < diN) {
            const int dio = diBase + dl;
#pragma unroll
            for (int t = 0; t < 2; ++t) {
#pragma unroll
                for (int r = 0; r < 4; ++r) {
                    int mp = 4 * q + r;
                    int dj = t * 8 + n15 - mp;
                    if (dj >= 0 && dj <= 8 && (t == 0 || n15 >= 8)) {
                        out[base + (size_t)(dio * 9 + dj) * 8192 + mp] = acc[dl][t][r];
                    }
                }
            }
        }
    }
}

extern "C" void kernel_launch(void* const* d_in, const int* in_sizes, int n_in,
                              void* d_out, int out_size, void* d_ws, size_t ws_size,
                              hipStream_t stream) {
    const float* f1 = (const float*)d_in[0];
    const float* f2 = (const float*)d_in[1];
    float* out = (float*)d_out;
    // grid: 8 batches (low bits -> XCD partition) x 2 di-halves x 8 h-tiles x 8 w-tiles = 1024
    // 2 blocks/CU resident (62 KB LDS, <=128 regs) -> 16 waves/CU
    corr_kernel<<<dim3(1024), dim3(512), 0, stream>>>(f1, f2, out);
}